// Round 4
// baseline (122.454 us; speedup 1.0000x reference)
//
#include <hip/hip_runtime.h>
#include <math.h>

// Problem constants (fixed by setup_inputs): B=8, C=32, H=256, W=256, step=32.
#define BB 8
#define CC 32
#define HH 256
#define WW 256
#define CHW (CC * HH * WW)   // 2097152
#define HW  (HH * WW)        // 65536
#define NTERM 12
#define CH_PER_ITER 4

__global__ __launch_bounds__(256)
void symctrl2_kernel(const float* __restrict__ x,
                     const float* __restrict__ s,
                     const float* __restrict__ w,
                     const float* __restrict__ w_param,
                     const float* __restrict__ b_param,
                     float* __restrict__ out) {
    const int bh = blockIdx.x;          // 0 .. B*H-1
    const int b  = bh >> 8;             // / HH
    const int h  = bh & (HH - 1);
    const int i  = threadIdx.x;         // 0 .. 255 (position along W)

    __shared__ float w_row[WW];
    __shared__ float sg[11];
    __shared__ float x_lds[CH_PER_ITER][WW];

    // Stage the w row for this (b,h)
    const float* wrow_g = w + ((size_t)b * HH + h) * WW;
    w_row[i] = wrow_g[i];

    // Gates: sigmoid(w_param * s[b,k] + b_param), k = 0..10
    if (i < 11) {
        float v = w_param[0] * s[b * 11 + i] + b_param[0];
        sg[i] = 1.0f / (1.0f + expf(-v));
    }
    __syncthreads();

    // Per-thread: 12 (source index, gated weight) pairs. Weight and x share src.
    int   src[NTERM];
    float gw[NTERM];
    src[0] = i;
    gw[0]  = w_row[i];
    #pragma unroll
    for (int k = 1; k <= 7; ++k) {             // circular shifts by 32*k
        int sidx = (i - 32 * k) & (WW - 1);
        src[k] = sidx;
        gw[k]  = sg[k - 1] * w_row[sidx];
    }
    #pragma unroll
    for (int j = 0; j < 4; ++j) {              // reflections about c = 32*(j+1)-1
        int c    = 32 * (j + 1) - 1;
        int sidx = (c - i) & (WW - 1);
        src[8 + j] = sidx;
        gw[8 + j]  = sg[7 + j] * w_row[sidx];
    }
    float den = 0.0f;
    #pragma unroll
    for (int k = 0; k < NTERM; ++k) den += gw[k];
    const float rden = 1.0f / den;

    // Sweep channels, 4 rows at a time.
    const float* xb = x   + (size_t)b * CHW + (size_t)h * WW;
    float*       ob = out + (size_t)b * CHW + (size_t)h * WW;

    const int cc = threadIdx.x >> 6;           // 0..3: which of the 4 rows I load
    const int p4 = (threadIdx.x & 63) << 2;    // float4 position within the row

    for (int c0 = 0; c0 < CC; c0 += CH_PER_ITER) {
        // Coalesced float4 load: 64 lanes x 16B per row, 4 rows per block iter.
        const float4 v = *reinterpret_cast<const float4*>(
            xb + (size_t)(c0 + cc) * HW + p4);
        *reinterpret_cast<float4*>(&x_lds[cc][p4]) = v;
        __syncthreads();

        #pragma unroll
        for (int c = 0; c < CH_PER_ITER; ++c) {
            float num = 0.0f;
            #pragma unroll
            for (int k = 0; k < NTERM; ++k)
                num = fmaf(gw[k], x_lds[c][src[k]], num);
            ob[(size_t)(c0 + c) * HW + i] = num * rden;
        }
        __syncthreads();   // protect x_lds before next iteration's overwrite
    }
}

extern "C" void kernel_launch(void* const* d_in, const int* in_sizes, int n_in,
                              void* d_out, int out_size, void* d_ws, size_t ws_size,
                              hipStream_t stream) {
    const float* x  = (const float*)d_in[0];
    const float* s  = (const float*)d_in[1];
    const float* w  = (const float*)d_in[2];
    const float* wp = (const float*)d_in[3];
    const float* bp = (const float*)d_in[4];
    float* out = (float*)d_out;

    dim3 grid(BB * HH);   // 2048 blocks, one per (b,h) row
    dim3 block(WW);       // 256 threads, one per position i
    symctrl2_kernel<<<grid, block, 0, stream>>>(x, s, w, wp, bp, out);
}